// Round 1
// baseline (38847.940 us; speedup 1.0000x reference)
//
#include <hip/hip_runtime.h>
#include <hip/hip_bf16.h>
#include <cstdint>
#include <cstddef>

// Problem constants
#define TT 1024
#define BB 32
#define DD 1024
#define HH 512
#define GG 2048  // 4H

__device__ __forceinline__ float sigm(float x) { return 1.0f / (1.0f + __expf(-x)); }
__device__ __forceinline__ float tanh_fast(float x) { return 2.0f / (1.0f + __expf(-2.0f * x)) - 1.0f; }

// ---------------------------------------------------------------------------
// init: zero h ping-pong buffers (2 dirs x 2 parity x 16384) + c (2 x 16384),
// set logits[t*32+b] = b_fc[0].  hc = 98304 floats, logits = 32768 floats.
// ---------------------------------------------------------------------------
__global__ __launch_bounds__(256) void init_kernel(float* __restrict__ hc,
                                                   float* __restrict__ logits,
                                                   const float* __restrict__ b_fc) {
    int i = blockIdx.x * 256 + threadIdx.x;
    if (i < 98304) {
        hc[i] = 0.0f;
    } else {
        logits[i - 98304] = b_fc[0];
    }
}

// ---------------------------------------------------------------------------
// Phase 1: xg[t][b][g] = sum_d x[b][t][d] * Wx[d][g] + bias[g], stored bf16.
// Row index m = t*32 + b so output [t][b][g] is contiguous in g.
// 64x64 tile, 256 threads, each thread 4x4 micro-tile, K-chunks of 16.
// ---------------------------------------------------------------------------
__global__ __launch_bounds__(256) void gemm_xg(const float* __restrict__ x,
                                               const float* __restrict__ Wx_f,
                                               const float* __restrict__ b_f,
                                               const float* __restrict__ Wx_b,
                                               const float* __restrict__ b_b,
                                               __hip_bfloat16* __restrict__ xg_f,
                                               __hip_bfloat16* __restrict__ xg_b) {
    const int dir = blockIdx.z;
    const float* __restrict__ W = dir ? Wx_b : Wx_f;
    const float* __restrict__ bias = dir ? b_b : b_f;
    __hip_bfloat16* __restrict__ out = dir ? xg_b : xg_f;

    const int g0 = blockIdx.x * 64;
    const int m0 = blockIdx.y * 64;

    __shared__ float As[16][68];  // As[kk][m] = A[m0+m][k0+kk]
    __shared__ float Bs[16][68];  // Bs[kk][g] = W[k0+kk][g0+g]

    const int tid = threadIdx.x;
    const int tx = tid & 15;        // 0..15 -> 4 output cols
    const int ty = tid >> 4;        // 0..15 -> 4 output rows

    float acc[4][4] = {};

    for (int k0 = 0; k0 < DD; k0 += 16) {
        // Load A tile: thread -> kk = tid%16, m = tid/16 + 16*i
        {
            const int kk = tid & 15;
            const int mb = tid >> 4;
#pragma unroll
            for (int i = 0; i < 4; i++) {
                const int m = mb + 16 * i;
                const int gm = m0 + m;
                const int t = gm >> 5;
                const int b = gm & 31;
                As[kk][m] = x[((size_t)b * TT + t) * DD + k0 + kk];
            }
        }
        // Load B tile: g = tid%64, kk = tid/64 + 4*i
        {
            const int g = tid & 63;
            const int kb = tid >> 6;
#pragma unroll
            for (int i = 0; i < 4; i++) {
                const int kk = kb + 4 * i;
                Bs[kk][g] = W[(size_t)(k0 + kk) * GG + g0 + g];
            }
        }
        __syncthreads();
#pragma unroll
        for (int kk = 0; kk < 16; kk++) {
            float a[4], bv[4];
#pragma unroll
            for (int i = 0; i < 4; i++) a[i] = As[kk][ty * 4 + i];
#pragma unroll
            for (int j = 0; j < 4; j++) bv[j] = Bs[kk][tx * 4 + j];
#pragma unroll
            for (int i = 0; i < 4; i++)
#pragma unroll
                for (int j = 0; j < 4; j++) acc[i][j] += a[i] * bv[j];
        }
        __syncthreads();
    }

#pragma unroll
    for (int i = 0; i < 4; i++) {
        const int gm = m0 + ty * 4 + i;
        const int t = gm >> 5;
        const int b = gm & 31;
#pragma unroll
        for (int j = 0; j < 4; j++) {
            const int gg = g0 + tx * 4 + j;
            out[((size_t)t * BB + b) * GG + gg] = __float2bfloat16(acc[i][j] + bias[gg]);
        }
    }
}

// ---------------------------------------------------------------------------
// Phase 2: one kernel per timestep. grid = (16 jb, 4 bq, 2 dir), 256 threads.
// Block covers 32 h-outputs (j-slice) x 8 batch rows. Thread = one (b, j):
// 4 gate dot products of length 512 against h_prev staged in LDS.
// h ping-pongs between two buffers by step parity; c updated in place.
// Fused FC contribution reduced per 32-lane group -> atomicAdd(logits).
// ---------------------------------------------------------------------------
__global__ __launch_bounds__(256) void step_kernel(const __hip_bfloat16* __restrict__ xg_f,
                                                   const __hip_bfloat16* __restrict__ xg_b,
                                                   const float* __restrict__ Wh_f,
                                                   const float* __restrict__ Wh_b,
                                                   float* __restrict__ hbufs,
                                                   float* __restrict__ cbufs,
                                                   const float* __restrict__ wfc,
                                                   float* __restrict__ logits,
                                                   int s) {
    const int dir = blockIdx.z;
    const int t = dir ? (TT - 1 - s) : s;
    const __hip_bfloat16* __restrict__ xg = dir ? xg_b : xg_f;
    const float* __restrict__ Wh = dir ? Wh_b : Wh_f;
    float* __restrict__ h_read = hbufs + dir * 32768 + (s & 1) * 16384;
    float* __restrict__ h_write = hbufs + dir * 32768 + ((s + 1) & 1) * 16384;
    float* __restrict__ cbuf = cbufs + dir * 16384;

    const int tid = threadIdx.x;
    const int j = blockIdx.x * 32 + (tid & 31);   // h-output index within [0,512)
    const int b0 = blockIdx.y * 8;
    const int b = b0 + (tid >> 5);

    __shared__ float h_lds[4096];  // h_prev for 8 batch rows x 512
    for (int i = tid; i < 4096; i += 256) h_lds[i] = h_read[b0 * 512 + i];
    __syncthreads();

    const float* __restrict__ hrow = &h_lds[(b - b0) * 512];
    const float* __restrict__ Whj = Wh + j;

    float ai = 0.f, af = 0.f, ag = 0.f, ao = 0.f;
#pragma unroll 4
    for (int k = 0; k < 512; k++) {
        const float hv = hrow[k];
        const float* __restrict__ wr = Whj + (size_t)k * GG;
        ai += hv * wr[0];
        af += hv * wr[512];
        ag += hv * wr[1024];
        ao += hv * wr[1536];
    }

    const size_t xgbase = ((size_t)t * BB + b) * GG + j;
    const float pi = ai + __bfloat162float(xg[xgbase]);
    const float pf = af + __bfloat162float(xg[xgbase + 512]);
    const float pg = ag + __bfloat162float(xg[xgbase + 1024]);
    const float po = ao + __bfloat162float(xg[xgbase + 1536]);

    const float gi = sigm(pi);
    const float gf = sigm(pf);
    const float gc = tanh_fast(pg);
    const float go = sigm(po);

    const int cidx = b * 512 + j;
    const float c_new = gf * cbuf[cidx] + gi * gc;
    cbuf[cidx] = c_new;
    const float h_new = go * tanh_fast(c_new);
    h_write[cidx] = h_new;

    // fused final-FC contribution: sum over j of h_new * W_fc[dir*512 + j]
    float contrib = h_new * wfc[dir * 512 + j];
    contrib += __shfl_down(contrib, 16, 32);
    contrib += __shfl_down(contrib, 8, 32);
    contrib += __shfl_down(contrib, 4, 32);
    contrib += __shfl_down(contrib, 2, 32);
    contrib += __shfl_down(contrib, 1, 32);
    if ((tid & 31) == 0) atomicAdd(&logits[t * BB + b], contrib);
}

// ---------------------------------------------------------------------------
// Final: out[b][t] = sigmoid(logits[t][b])
// ---------------------------------------------------------------------------
__global__ __launch_bounds__(256) void final_kernel(const float* __restrict__ logits,
                                                    float* __restrict__ out) {
    const int i = blockIdx.x * 256 + threadIdx.x;  // i = b*1024 + t
    const int b = i >> 10;
    const int t = i & 1023;
    out[i] = sigm(logits[t * BB + b]);
}

extern "C" void kernel_launch(void* const* d_in, const int* in_sizes, int n_in,
                              void* d_out, int out_size, void* d_ws, size_t ws_size,
                              hipStream_t stream) {
    const float* x    = (const float*)d_in[0];
    const float* Wx_f = (const float*)d_in[1];
    const float* Wh_f = (const float*)d_in[2];
    const float* b_f  = (const float*)d_in[3];
    const float* Wx_b = (const float*)d_in[4];
    const float* Wh_b = (const float*)d_in[5];
    const float* b_b  = (const float*)d_in[6];
    const float* W_fc = (const float*)d_in[7];
    const float* b_fc = (const float*)d_in[8];
    float* out = (float*)d_out;

    // Workspace layout:
    //   xg_f bf16 [T][B][4H]  : 134217728 B
    //   xg_b bf16 [T][B][4H]  : 134217728 B
    //   hbufs fp32 [2][2][16384] : 262144 B   (dir x parity)
    //   cbufs fp32 [2][16384]    : 131072 B
    //   logits fp32 [T*B]        : 131072 B
    const size_t need = 134217728ULL * 2 + 262144ULL + 131072ULL + 131072ULL;
    if (ws_size < need) return;  // workspace too small; fail loudly via mismatch

    uint8_t* ws = (uint8_t*)d_ws;
    __hip_bfloat16* xg_f = (__hip_bfloat16*)ws;
    __hip_bfloat16* xg_b = (__hip_bfloat16*)(ws + 134217728ULL);
    float* hbufs = (float*)(ws + 268435456ULL);
    float* cbufs = hbufs + 65536;
    float* logits = cbufs + 32768;

    // init h/c/logits (hbufs..cbufs are contiguous: 98304 floats)
    init_kernel<<<512, 256, 0, stream>>>(hbufs, logits, b_fc);

    // phase 1: input projections for both directions
    gemm_xg<<<dim3(GG / 64, (TT * BB) / 64, 2), 256, 0, stream>>>(
        x, Wx_f, b_f, Wx_b, b_b, xg_f, xg_b);

    // phase 2: 1024 sequential recurrence steps (fwd + bwd in each launch)
    for (int s = 0; s < TT; s++) {
        step_kernel<<<dim3(16, 4, 2), 256, 0, stream>>>(
            xg_f, xg_b, Wh_f, Wh_b, hbufs, cbufs, W_fc, logits, s);
    }

    // epilogue
    final_kernel<<<(BB * TT) / 256, 256, 0, stream>>>(logits, out);
}

// Round 2
// 16856.911 us; speedup vs baseline: 2.3046x; 2.3046x over previous
//
#include <hip/hip_runtime.h>
#include <hip/hip_bf16.h>
#include <cstdint>
#include <cstddef>

// Problem constants
#define TT 1024
#define BB 32
#define DD 1024
#define HH 512
#define GG 2048  // 4H

typedef _Float16 h2f16 __attribute__((ext_vector_type(2)));

__device__ __forceinline__ float sigm(float x) { return 1.0f / (1.0f + __expf(-x)); }
__device__ __forceinline__ float tanh_fast(float x) { return 2.0f / (1.0f + __expf(-2.0f * x)) - 1.0f; }

__device__ __forceinline__ float dot2(h2f16 a, h2f16 b, float c) {
#if __has_builtin(__builtin_amdgcn_fdot2)
    return __builtin_amdgcn_fdot2(a, b, c, false);
#else
    return c + (float)a.x * (float)b.x + (float)a.y * (float)b.y;
#endif
}

// ---------------------------------------------------------------------------
// init: zero packed-h ping-pong buffers (32768 u32) + counters (64 ints),
// seed logits[t*32+b] = b_fc[0] (32768 floats).
// ---------------------------------------------------------------------------
__global__ __launch_bounds__(256) void init_kernel(unsigned int* __restrict__ hp_u,
                                                   float* __restrict__ logits,
                                                   int* __restrict__ cnt,
                                                   const float* __restrict__ b_fc) {
    int i = blockIdx.x * 256 + threadIdx.x;
    if (i < 32768) {
        hp_u[i] = 0u;
    } else if (i < 65536) {
        logits[i - 32768] = b_fc[0];
    } else if (i < 65600) {
        cnt[i - 65536] = 0;
    }
}

// ---------------------------------------------------------------------------
// Phase 1: xg = x@Wx + b (fp32 compute, bf16 store).
// Output layout (recurrence-friendly): xg2[t][blk(128)][b(32)][jloc(4)][gate(4)]
// where g_global = gate*512 + blk*4 + jloc. 64x64 tile, 256 threads, 4x4 micro.
// ---------------------------------------------------------------------------
__global__ __launch_bounds__(256) void gemm_xg(const float* __restrict__ x,
                                               const float* __restrict__ Wx_f,
                                               const float* __restrict__ b_f,
                                               const float* __restrict__ Wx_b,
                                               const float* __restrict__ b_b,
                                               __hip_bfloat16* __restrict__ xg_f,
                                               __hip_bfloat16* __restrict__ xg_b) {
    const int dir = blockIdx.z;
    const float* __restrict__ W = dir ? Wx_b : Wx_f;
    const float* __restrict__ bias = dir ? b_b : b_f;
    __hip_bfloat16* __restrict__ out = dir ? xg_b : xg_f;

    const int g0 = blockIdx.x * 64;
    const int m0 = blockIdx.y * 64;

    __shared__ float As[16][68];  // As[kk][m]
    __shared__ float Bs[16][68];  // Bs[kk][g]

    const int tid = threadIdx.x;
    const int tx = tid & 15;
    const int ty = tid >> 4;

    float acc[4][4] = {};

    for (int k0 = 0; k0 < DD; k0 += 16) {
        {
            const int kk = tid & 15;
            const int mb = tid >> 4;
#pragma unroll
            for (int i = 0; i < 4; i++) {
                const int m = mb + 16 * i;
                const int gm = m0 + m;
                const int t = gm >> 5;
                const int b = gm & 31;
                As[kk][m] = x[((size_t)b * TT + t) * DD + k0 + kk];
            }
        }
        {
            const int g = tid & 63;
            const int kb = tid >> 6;
#pragma unroll
            for (int i = 0; i < 4; i++) {
                const int kk = kb + 4 * i;
                Bs[kk][g] = W[(size_t)(k0 + kk) * GG + g0 + g];
            }
        }
        __syncthreads();
#pragma unroll
        for (int kk = 0; kk < 16; kk++) {
            float a[4], bv[4];
#pragma unroll
            for (int i = 0; i < 4; i++) a[i] = As[kk][ty * 4 + i];
#pragma unroll
            for (int j = 0; j < 4; j++) bv[j] = Bs[kk][tx * 4 + j];
#pragma unroll
            for (int i = 0; i < 4; i++)
#pragma unroll
                for (int j = 0; j < 4; j++) acc[i][j] += a[i] * bv[j];
        }
        __syncthreads();
    }

    const int gate = g0 >> 9;              // which gate block (512-wide)
    const int blkbase = (g0 & 511) >> 2;   // recurrence block index base
#pragma unroll
    for (int i = 0; i < 4; i++) {
        const int gm = m0 + ty * 4 + i;
        const int t = gm >> 5;
        const int b = gm & 31;
        __hip_bfloat16* orow =
            out + ((size_t)(t * 128 + blkbase + tx) * 32 + b) * 16 + gate;
#pragma unroll
        for (int j = 0; j < 4; j++) {
            orow[j * 4] = __float2bfloat16(acc[i][j] + bias[g0 + tx * 4 + j]);
        }
    }
}

// ---------------------------------------------------------------------------
// Phase 2: persistent bidirectional LSTM recurrence.
// 256 blocks x 1024 threads; blocks 0..127 = fwd, 128..255 = bwd.
// Block owns j-slice of 4 h-outputs; its 16 Wh columns live in LDS (fp16)
// for all 1024 steps. h exchanged via agent-scope atomics (packed fp16).
// Per-dir flag barrier with watchdog valve. c state lives in registers.
// Thread roles: b=tid&31, kk0=(tid>>5)&1, j=(tid>>6)&3, kkh=tid>>8.
// ---------------------------------------------------------------------------
__global__ __launch_bounds__(1024, 4) void lstm_persist(
    const __hip_bfloat16* __restrict__ xg_f,
    const __hip_bfloat16* __restrict__ xg_b,
    const float* __restrict__ Wh_f,
    const float* __restrict__ Wh_b,
    const float* __restrict__ wfc,
    unsigned int* __restrict__ hpack,
    float* __restrict__ logits,
    int* __restrict__ cnt) {

    __shared__ _Float16 W_lds[16 * 516];   // [col=g*4+j][k], 16.5 KB
    __shared__ _Float16 h_lds[32 * 516];   // [b][k], 33 KB
    __shared__ float red[128 * 17];        // [(b*4+j)][kkh*4+g], 8.7 KB
    __shared__ int dead;

    const int tid = threadIdx.x;
    const int bid = blockIdx.x;
    const int dir = bid >> 7;
    const int blk = bid & 127;
    const int j0  = blk * 4;

    const float* __restrict__ Wh = dir ? Wh_b : Wh_f;
    const unsigned short* __restrict__ xg =
        (const unsigned short*)(dir ? xg_b : xg_f);
    unsigned int* hp = hpack + dir * 16384;  // [parity][8192] u32
    int* mycnt = cnt + dir * 32;

    // ---- load Wh slice to LDS (fp16), transposed [col][k] ----
    {
        const int c = tid >> 6;      // 0..15
        const int lane = tid & 63;
        const int g = c >> 2, jl = c & 3;
        const int gcol = g * 512 + j0 + jl;
#pragma unroll
        for (int q = 0; q < 8; q++) {
            const int k = q * 64 + lane;
            W_lds[c * 516 + k] = (_Float16)Wh[(size_t)k * GG + gcol];
        }
    }
    if (tid == 0) dead = 0;

    const int b   = tid & 31;
    const int kk0 = (tid >> 5) & 1;
    const int jj  = (tid >> 6) & 3;
    const int kkh = tid >> 8;            // 0..3
    const int kk  = (kkh << 1) | kk0;    // 0..7 -> k range [kk*64, kk*64+64)

    const int r = tid;                   // final role (r<128): bF=r>>2, jF=r&3
    float c_reg = 0.0f;
    float wfc_reg = 0.0f;
    if (r < 128) wfc_reg = wfc[dir * 512 + j0 + (r & 3)];

    const h2f16* W2 = (const h2f16*)W_lds;
    const h2f16* H2 = (const h2f16*)h_lds;
    unsigned int* hl_u = (unsigned int*)h_lds;

    __syncthreads();  // W_lds + dead ready

    for (int s = 0; s < TT; s++) {
        const int t = dir ? (TT - 1 - s) : s;

        // ---- stage h(s) from global (agent-scope, packed fp16) ----
        {
            const unsigned int* src = hp + (s & 1) * 8192;
#pragma unroll
            for (int q = 0; q < 8; q++) {
                const int idx = q * 1024 + tid;
                unsigned int v = __hip_atomic_load(src + idx, __ATOMIC_RELAXED,
                                                   __HIP_MEMORY_SCOPE_AGENT);
                hl_u[(idx >> 8) * 258 + (idx & 255)] = v;
            }
        }
        __syncthreads();

        // ---- partial gate dots over this thread's 64-k window ----
        float a0 = 0.f, a1 = 0.f, a2 = 0.f, a3 = 0.f;
        {
            const h2f16* hr = H2 + b * 258 + kk * 32;
            const h2f16* w0 = W2 + (0 * 4 + jj) * 258 + kk * 32;
            const h2f16* w1 = W2 + (1 * 4 + jj) * 258 + kk * 32;
            const h2f16* w2 = W2 + (2 * 4 + jj) * 258 + kk * 32;
            const h2f16* w3 = W2 + (3 * 4 + jj) * 258 + kk * 32;
#pragma unroll 8
            for (int p = 0; p < 32; p++) {
                h2f16 hv = hr[p];
                a0 = dot2(hv, w0[p], a0);
                a1 = dot2(hv, w1[p], a1);
                a2 = dot2(hv, w2[p], a2);
                a3 = dot2(hv, w3[p], a3);
            }
        }
        // reduce kk0 pairs (lane ^ 32, same wave)
        a0 += __shfl_xor(a0, 32, 64);
        a1 += __shfl_xor(a1, 32, 64);
        a2 += __shfl_xor(a2, 32, 64);
        a3 += __shfl_xor(a3, 32, 64);
        if (kk0 == 0) {
            float* rp = &red[((b << 2) | jj) * 17 + kkh * 4];
            rp[0] = a0; rp[1] = a1; rp[2] = a2; rp[3] = a3;
        }
        __syncthreads();

        // ---- gate math + h/c update + fused FC (threads r < 128) ----
        if (r < 128) {
            const int bF = r >> 2;
            float p0 = 0.f, p1 = 0.f, p2 = 0.f, p3 = 0.f;
#pragma unroll
            for (int kq = 0; kq < 4; kq++) {
                const float* rp = &red[r * 17 + kq * 4];
                p0 += rp[0]; p1 += rp[1]; p2 += rp[2]; p3 += rp[3];
            }
            const size_t xoff = ((size_t)(t * 128 + blk) << 9) + ((size_t)r << 2);
            ushort4 xv = *(const ushort4*)(xg + xoff);
            p0 += __uint_as_float((unsigned int)xv.x << 16);
            p1 += __uint_as_float((unsigned int)xv.y << 16);
            p2 += __uint_as_float((unsigned int)xv.z << 16);
            p3 += __uint_as_float((unsigned int)xv.w << 16);

            const float gi = sigm(p0);
            const float gf = sigm(p1);
            const float gc = tanh_fast(p2);
            const float go = sigm(p3);
            c_reg = gf * c_reg + gi * gc;
            const float hval = go * tanh_fast(c_reg);

            // pack fp16 pair with j-neighbor, agent-scope store
            const float hpart = __shfl_xor(hval, 1, 64);
            unsigned int* dst = hp + ((s + 1) & 1) * 8192;
            if ((r & 1) == 0) {
                union { h2f16 h2; unsigned int u; } cvt;
                cvt.h2.x = (_Float16)hval;
                cvt.h2.y = (_Float16)hpart;
                __hip_atomic_store(dst + bF * 256 + ((j0 + (r & 3)) >> 1), cvt.u,
                                   __ATOMIC_RELAXED, __HIP_MEMORY_SCOPE_AGENT);
            }
            // fused final-FC contribution
            float contrib = hval * wfc_reg;
            contrib += __shfl_xor(contrib, 1, 64);
            contrib += __shfl_xor(contrib, 2, 64);
            if ((r & 3) == 0) atomicAdd(&logits[t * BB + bF], contrib);
        }

        // ---- per-dir grid barrier with watchdog ----
        __syncthreads();
        if (tid == 0) {
            const int tgt = 128 * (s + 1);
            __hip_atomic_fetch_add(mycnt, 1, __ATOMIC_RELEASE,
                                   __HIP_MEMORY_SCOPE_AGENT);
            int it = 0;
            while (__hip_atomic_load(mycnt, __ATOMIC_RELAXED,
                                     __HIP_MEMORY_SCOPE_AGENT) < tgt) {
                __builtin_amdgcn_s_sleep(8);
                if (++it > (1 << 21)) { dead = 1; break; }  // ~0.4s valve
            }
            __builtin_amdgcn_fence(__ATOMIC_ACQUIRE, "agent");
        }
        __syncthreads();
        if (dead) break;  // fail visibly instead of hanging
    }
}

// ---------------------------------------------------------------------------
// Final: out[b][t] = sigmoid(logits[t][b])
// ---------------------------------------------------------------------------
__global__ __launch_bounds__(256) void final_kernel(const float* __restrict__ logits,
                                                    float* __restrict__ out) {
    const int i = blockIdx.x * 256 + threadIdx.x;  // i = b*1024 + t
    const int b = i >> 10;
    const int t = i & 1023;
    out[i] = sigm(logits[t * BB + b]);
}

extern "C" void kernel_launch(void* const* d_in, const int* in_sizes, int n_in,
                              void* d_out, int out_size, void* d_ws, size_t ws_size,
                              hipStream_t stream) {
    const float* x    = (const float*)d_in[0];
    const float* Wx_f = (const float*)d_in[1];
    const float* Wh_f = (const float*)d_in[2];
    const float* b_f  = (const float*)d_in[3];
    const float* Wx_b = (const float*)d_in[4];
    const float* Wh_b = (const float*)d_in[5];
    const float* b_b  = (const float*)d_in[6];
    const float* W_fc = (const float*)d_in[7];
    const float* b_fc = (const float*)d_in[8];
    float* out = (float*)d_out;

    // Workspace layout:
    //   xg_f bf16 [t][blk][b][j][gate] : 134217728 B
    //   xg_b bf16 same                 : 134217728 B
    //   hpack u32 [dir][parity][8192]  : 131072 B   (packed fp16 h pairs)
    //   logits fp32 [T*B]              : 131072 B
    //   counters int [64]              : 256 B
    const size_t XG_BYTES = 134217728ULL;
    const size_t HP_OFF = 2 * XG_BYTES;
    const size_t LG_OFF = HP_OFF + 131072ULL;
    const size_t CNT_OFF = LG_OFF + 131072ULL;
    const size_t need = CNT_OFF + 256ULL;
    if (ws_size < need) return;

    uint8_t* ws = (uint8_t*)d_ws;
    __hip_bfloat16* xg_f = (__hip_bfloat16*)ws;
    __hip_bfloat16* xg_b = (__hip_bfloat16*)(ws + XG_BYTES);
    unsigned int* hpack = (unsigned int*)(ws + HP_OFF);
    float* logits = (float*)(ws + LG_OFF);
    int* cnt = (int*)(ws + CNT_OFF);

    init_kernel<<<257, 256, 0, stream>>>(hpack, logits, cnt, b_fc);

    gemm_xg<<<dim3(GG / 64, (TT * BB) / 64, 2), 256, 0, stream>>>(
        x, Wx_f, b_f, Wx_b, b_b, xg_f, xg_b);

    lstm_persist<<<256, 1024, 0, stream>>>(
        xg_f, xg_b, Wh_f, Wh_b, W_fc, hpack, logits, cnt);

    final_kernel<<<(BB * TT) / 256, 256, 0, stream>>>(logits, out);
}

// Round 3
// 9175.624 us; speedup vs baseline: 4.2338x; 1.8371x over previous
//
#include <hip/hip_runtime.h>
#include <hip/hip_bf16.h>
#include <cstdint>
#include <cstddef>

// Problem constants
#define TT 1024
#define BB 32
#define DD 1024
#define HH 512
#define GG 2048  // 4H

typedef _Float16 f16x8 __attribute__((ext_vector_type(8)));
typedef _Float16 f16x4 __attribute__((ext_vector_type(4)));
typedef float    f32x4 __attribute__((ext_vector_type(4)));

__device__ __forceinline__ float sigm(float x) { return 1.0f / (1.0f + __expf(-x)); }
__device__ __forceinline__ float tanh_fast(float x) { return 2.0f / (1.0f + __expf(-2.0f * x)) - 1.0f; }

// ---------------------------------------------------------------------------
// init: zero packed-h ping-pong buffers (32768 u32) + counters (64 ints),
// seed logits[t*32+b] = b_fc[0] (32768 floats).
// ---------------------------------------------------------------------------
__global__ __launch_bounds__(256) void init_kernel(unsigned int* __restrict__ hp_u,
                                                   float* __restrict__ logits,
                                                   int* __restrict__ cnt,
                                                   const float* __restrict__ b_fc) {
    int i = blockIdx.x * 256 + threadIdx.x;
    if (i < 32768) {
        hp_u[i] = 0u;
    } else if (i < 65536) {
        logits[i - 32768] = b_fc[0];
    } else if (i < 65600) {
        cnt[i - 65536] = 0;
    }
}

// ---------------------------------------------------------------------------
// transpose_f16: in fp32 [K][N] row-major -> out f16 [N][K].
// 32x32 LDS tiles, 256 threads. Used for Wx (1024x2048) and Wh (512x2048).
// ---------------------------------------------------------------------------
__global__ __launch_bounds__(256) void transpose_f16(const float* __restrict__ in,
                                                     _Float16* __restrict__ out,
                                                     int K, int N) {
    __shared__ float tile[32][33];
    const int tx = threadIdx.x & 31, ty = threadIdx.x >> 5;
    const int n0 = blockIdx.x * 32, k0 = blockIdx.y * 32;
#pragma unroll
    for (int j = 0; j < 4; j++)
        tile[ty + 8 * j][tx] = in[(size_t)(k0 + ty + 8 * j) * N + n0 + tx];
    __syncthreads();
#pragma unroll
    for (int j = 0; j < 4; j++)
        out[(size_t)(n0 + ty + 8 * j) * K + k0 + tx] = (_Float16)tile[tx][ty + 8 * j];
}

// ---------------------------------------------------------------------------
// Phase 1: xg = x@Wx + b via MFMA f16 (fp32 accumulate), stored f16.
// Tiles: block = 128(m) x 128(n), 256 threads (4 waves), K-step 64.
// Wave w: m-tiles {2w, 2w+1} x all 8 n-tiles -> 16 f32x4 accs.
// A from x fp32 (convert on stage), B from pre-transposed WxT f16 [n][k].
// Output layout (recurrence-native):
//   xg[t][blk32][b32][gate4][jl16],  n = gate*512 + blk*16 + jl
//   idx = ((t*32+blk)*32 + b)*64 + gate*16 + jl
// ---------------------------------------------------------------------------
__global__ __launch_bounds__(256) void gemm_xg(const float* __restrict__ x,
                                               const _Float16* __restrict__ WxT_f,
                                               const float* __restrict__ b_f,
                                               const _Float16* __restrict__ WxT_b,
                                               const float* __restrict__ b_b,
                                               _Float16* __restrict__ xg_f,
                                               _Float16* __restrict__ xg_b) {
    const int dir = blockIdx.z;
    const _Float16* __restrict__ WxT = dir ? WxT_b : WxT_f;
    const float* __restrict__ bias = dir ? b_b : b_f;
    _Float16* __restrict__ out = dir ? xg_b : xg_f;

    const int n0 = blockIdx.x * 128;
    const int m0 = blockIdx.y * 128;

    __shared__ _Float16 A_lds[128 * 72];  // [m][k], k padded 64->72
    __shared__ _Float16 B_lds[128 * 72];  // [n][k]

    const int tid = threadIdx.x;
    const int wave = tid >> 6;
    const int lane = tid & 63;
    const int jn = lane & 15;
    const int quad = lane >> 4;

    f32x4 acc[2][8] = {};

    for (int k0 = 0; k0 < DD; k0 += 64) {
        // ---- stage A: 128m x 64k fp32 -> f16 LDS ----
        {
            const int kq = tid & 15;          // float4 within 64 k
            const int mq = tid >> 4;          // 0..15
#pragma unroll
            for (int i = 0; i < 8; i++) {
                const int m = mq + 16 * i;
                const int gm = m0 + m;
                const int t = gm >> 5;
                const int b = gm & 31;
                const float4 v = *(const float4*)(x + ((size_t)b * TT + t) * DD + k0 + kq * 4);
                f16x4 f;
                f.x = (_Float16)v.x; f.y = (_Float16)v.y;
                f.z = (_Float16)v.z; f.w = (_Float16)v.w;
                *(f16x4*)(A_lds + m * 72 + kq * 4) = f;
            }
        }
        // ---- stage B: 128n x 64k f16 (already transposed) ----
        {
            const int kq = tid & 7;           // f16x8 within 64 k
            const int nq = tid >> 3;          // 0..31
#pragma unroll
            for (int i = 0; i < 4; i++) {
                const int n = nq + 32 * i;
                f16x8 w = *(const f16x8*)(WxT + (size_t)(n0 + n) * DD + k0 + kq * 8);
                *(f16x8*)(B_lds + n * 72 + kq * 8) = w;
            }
        }
        __syncthreads();
        // ---- compute ----
#pragma unroll
        for (int kc = 0; kc < 64; kc += 32) {
            const f16x8 a0 = *(const f16x8*)(A_lds + (wave * 32 + jn) * 72 + kc + quad * 8);
            const f16x8 a1 = *(const f16x8*)(A_lds + (wave * 32 + 16 + jn) * 72 + kc + quad * 8);
#pragma unroll
            for (int nt = 0; nt < 8; nt++) {
                const f16x8 bb = *(const f16x8*)(B_lds + (nt * 16 + jn) * 72 + kc + quad * 8);
                acc[0][nt] = __builtin_amdgcn_mfma_f32_16x16x32_f16(a0, bb, acc[0][nt], 0, 0, 0);
                acc[1][nt] = __builtin_amdgcn_mfma_f32_16x16x32_f16(a1, bb, acc[1][nt], 0, 0, 0);
            }
        }
        __syncthreads();
    }

    // ---- epilogue: add bias, store f16 in recurrence layout ----
    float bv[8];
#pragma unroll
    for (int nt = 0; nt < 8; nt++) bv[nt] = bias[n0 + nt * 16 + jn];
#pragma unroll
    for (int mt = 0; mt < 2; mt++) {
#pragma unroll
        for (int r = 0; r < 4; r++) {
            const int m = m0 + wave * 32 + mt * 16 + quad * 4 + r;
            const int t = m >> 5;
            const int b = m & 31;
            const size_t rowbase = ((size_t)t * 32) * 32;  // + blk later
#pragma unroll
            for (int nt = 0; nt < 8; nt++) {
                const int n = n0 + nt * 16 + jn;
                const int g = n >> 9;
                const int blkr = (n & 511) >> 4;
                const int jl = n & 15;
                const float val = acc[mt][nt][r] + bv[nt];
                out[((rowbase + (size_t)blkr * 32 + b)) * 64 + g * 16 + jl] = (_Float16)val;
            }
        }
    }
}

// ---------------------------------------------------------------------------
// Phase 2: persistent bidirectional LSTM recurrence via MFMA.
// 64 blocks x 512 threads; blocks 0..31 = fwd, 32..63 = bwd.
// Block owns 64 gate-cols: col = g*512 + blk*16 + jl (g<4, jl<16).
// Wave w (8 per block): mt = w&1 (b-half), g = w>>1 (gate). Each wave holds
// its 16 Wh B-fragments (K=512) in 64 VGPRs for all 1024 steps -> zero W LDS
// traffic. h staged in LDS f16 [32][520]. 16 chained mfma_16x16x32_f16.
// h exchanged via agent-scope packed-f16 atomics; per-dir monotone counter
// barrier with watchdog valve. c state in registers. FC logit fused.
// ---------------------------------------------------------------------------
__global__ __launch_bounds__(512) void lstm_persist(
    const _Float16* __restrict__ xg_f,
    const _Float16* __restrict__ xg_b,
    const _Float16* __restrict__ WhT_f,
    const _Float16* __restrict__ WhT_b,
    const float* __restrict__ wfc,
    unsigned int* __restrict__ hpack,
    float* __restrict__ logits,
    int* __restrict__ cnt) {

    __shared__ _Float16 h_lds[32 * 520];  // [b][k], k padded -> 33,280 B
    __shared__ float red[4 * 32 * 17];    // [g][b][jl pad 17] -> 8,704 B
    __shared__ int dead;

    const int tid = threadIdx.x;
    const int bid = blockIdx.x;
    const int dir = bid >> 5;
    const int blk = bid & 31;

    const _Float16* __restrict__ xg = dir ? xg_b : xg_f;
    const _Float16* __restrict__ WhT = dir ? WhT_b : WhT_f;
    unsigned int* hp = hpack + dir * 16384;  // [parity][8192] u32
    int* mycnt = cnt + dir * 32;

    // wave roles
    const int lane = tid & 63;
    const int wave = tid >> 6;
    const int mt = wave & 1;       // b-half: rows mt*16..+16
    const int g = wave >> 1;       // gate 0..3
    const int jl16 = lane & 15;
    const int quad = lane >> 4;

    // ---- preload Wh B-fragments into registers (once) ----
    // frag[i] covers k = 32*i + quad*8 + [0..8) for col g*512 + blk*16 + jl16
    f16x8 bfrag[16];
    {
        const _Float16* wcol = WhT + (size_t)(g * 512 + blk * 16 + jl16) * HH;
#pragma unroll
        for (int i = 0; i < 16; i++)
            bfrag[i] = *(const f16x8*)(wcol + i * 32 + quad * 8);
    }

    // gate-thread role: one (b, jl) per thread
    const int gb = tid >> 4;       // 0..31
    const int gjl = tid & 15;      // 0..15
    float c_reg = 0.0f;
    const float wfc_reg = wfc[dir * 512 + blk * 16 + gjl];

    // xg prefetch for step 0
    float xnext[4];
    {
        const int t0 = dir ? (TT - 1) : 0;
        const size_t base = (((size_t)t0 * 32 + blk) * 32 + gb) * 64 + gjl;
#pragma unroll
        for (int g4 = 0; g4 < 4; g4++) xnext[g4] = (float)xg[base + g4 * 16];
    }

    if (tid == 0) dead = 0;
    unsigned int* hl_u = (unsigned int*)h_lds;
    __syncthreads();

    for (int s = 0; s < TT; s++) {
        const int t = dir ? (TT - 1 - s) : s;

        // ---- stage h(s): 8192 packed u32 from global -> LDS ----
        {
            const unsigned int* src = hp + (s & 1) * 8192;
#pragma unroll
            for (int q = 0; q < 16; q++) {
                const int idx = q * 512 + tid;
                unsigned int v = __hip_atomic_load(src + idx, __ATOMIC_RELAXED,
                                                   __HIP_MEMORY_SCOPE_AGENT);
                hl_u[(idx >> 8) * 260 + (idx & 255)] = v;
            }
        }
        __syncthreads();

        // ---- MFMA: preact tile [16 b x 16 jl] for gate g, b-half mt ----
        {
            f32x4 acc = {0.f, 0.f, 0.f, 0.f};
            const _Float16* hrow = h_lds + (mt * 16 + jl16) * 520 + quad * 8;
#pragma unroll
            for (int i = 0; i < 16; i++) {
                const f16x8 a = *(const f16x8*)(hrow + 32 * i);
                acc = __builtin_amdgcn_mfma_f32_16x16x32_f16(a, bfrag[i], acc, 0, 0, 0);
            }
            // D: col = lane&15 (jl), row = quad*4 + r (b within half)
#pragma unroll
            for (int r = 0; r < 4; r++)
                red[(g * 32 + mt * 16 + quad * 4 + r) * 17 + jl16] = acc[r];
        }
        __syncthreads();

        // ---- gate math + h/c update + fused FC (all 512 threads) ----
        {
            const float p0 = red[(0 * 32 + gb) * 17 + gjl] + xnext[0];
            const float p1 = red[(1 * 32 + gb) * 17 + gjl] + xnext[1];
            const float p2 = red[(2 * 32 + gb) * 17 + gjl] + xnext[2];
            const float p3 = red[(3 * 32 + gb) * 17 + gjl] + xnext[3];

            const float gi = sigm(p0);
            const float gf = sigm(p1);
            const float gc = tanh_fast(p2);
            const float go = sigm(p3);
            c_reg = gf * c_reg + gi * gc;
            const float hval = go * tanh_fast(c_reg);

            // pack f16 pair with jl-neighbor, agent-scope store
            const float hpart = __shfl_xor(hval, 1);
            if ((gjl & 1) == 0) {
                union { struct { _Float16 lo, hi; } h; unsigned int u; } cvt;
                cvt.h.lo = (_Float16)hval;
                cvt.h.hi = (_Float16)hpart;
                unsigned int* dst = hp + ((s + 1) & 1) * 8192;
                __hip_atomic_store(dst + gb * 256 + blk * 8 + (gjl >> 1), cvt.u,
                                   __ATOMIC_RELAXED, __HIP_MEMORY_SCOPE_AGENT);
            }
            // fused final-FC contribution: reduce over this block's 16 jl
            float contrib = hval * wfc_reg;
            contrib += __shfl_xor(contrib, 1);
            contrib += __shfl_xor(contrib, 2);
            contrib += __shfl_xor(contrib, 4);
            contrib += __shfl_xor(contrib, 8);
            if (gjl == 0) atomicAdd(&logits[t * BB + gb], contrib);

            // prefetch xg for next step (overlaps barrier + h exchange)
            if (s + 1 < TT) {
                const int tn = dir ? (TT - 2 - s) : (s + 1);
                const size_t base = (((size_t)tn * 32 + blk) * 32 + gb) * 64 + gjl;
#pragma unroll
                for (int g4 = 0; g4 < 4; g4++) xnext[g4] = (float)xg[base + g4 * 16];
            }
        }

        // ---- per-dir grid barrier with watchdog ----
        __syncthreads();
        if (tid == 0) {
            const int tgt = 32 * (s + 1);
            __hip_atomic_fetch_add(mycnt, 1, __ATOMIC_RELEASE,
                                   __HIP_MEMORY_SCOPE_AGENT);
            int it = 0;
            while (__hip_atomic_load(mycnt, __ATOMIC_RELAXED,
                                     __HIP_MEMORY_SCOPE_AGENT) < tgt) {
                __builtin_amdgcn_s_sleep(1);
                if (++it > (1 << 22)) { dead = 1; break; }  // watchdog valve
            }
            __builtin_amdgcn_fence(__ATOMIC_ACQUIRE, "agent");
        }
        __syncthreads();
        if (dead) break;  // fail visibly instead of hanging
    }
}

// ---------------------------------------------------------------------------
// Final: out[b][t] = sigmoid(logits[t][b])
// ---------------------------------------------------------------------------
__global__ __launch_bounds__(256) void final_kernel(const float* __restrict__ logits,
                                                    float* __restrict__ out) {
    const int i = blockIdx.x * 256 + threadIdx.x;  // i = b*1024 + t
    const int b = i >> 10;
    const int t = i & 1023;
    out[i] = sigm(logits[t * BB + b]);
}

extern "C" void kernel_launch(void* const* d_in, const int* in_sizes, int n_in,
                              void* d_out, int out_size, void* d_ws, size_t ws_size,
                              hipStream_t stream) {
    const float* x    = (const float*)d_in[0];
    const float* Wx_f = (const float*)d_in[1];
    const float* Wh_f = (const float*)d_in[2];
    const float* b_f  = (const float*)d_in[3];
    const float* Wx_b = (const float*)d_in[4];
    const float* Wh_b = (const float*)d_in[5];
    const float* b_b  = (const float*)d_in[6];
    const float* W_fc = (const float*)d_in[7];
    const float* b_fc = (const float*)d_in[8];
    float* out = (float*)d_out;

    // Workspace layout (bytes):
    //   xg_f  f16 [t][blk][b][gate][jl] : 134,217,728
    //   xg_b  f16 same                  : 134,217,728
    //   hpack u32 [dir][parity][8192]   : 131,072
    //   logits fp32 [T*B]               : 131,072
    //   cnt   int [64]                  : 256 (+pad to 512)
    //   WxT_f f16 [2048][1024]          : 4,194,304
    //   WxT_b f16 [2048][1024]          : 4,194,304
    //   WhT_f f16 [2048][512]           : 2,097,152
    //   WhT_b f16 [2048][512]           : 2,097,152
    const size_t XG = 134217728ULL;
    const size_t HP_OFF   = 2 * XG;                    // 268,435,456
    const size_t LG_OFF   = HP_OFF + 131072ULL;
    const size_t CNT_OFF  = LG_OFF + 131072ULL;
    const size_t WXT_OFF  = CNT_OFF + 512ULL;
    const size_t WHT_OFF  = WXT_OFF + 2 * 4194304ULL;
    const size_t need     = WHT_OFF + 2 * 2097152ULL;
    if (ws_size < need) return;  // fail loudly via mismatch

    uint8_t* ws = (uint8_t*)d_ws;
    _Float16* xg_f = (_Float16*)ws;
    _Float16* xg_b = (_Float16*)(ws + XG);
    unsigned int* hpack = (unsigned int*)(ws + HP_OFF);
    float* logits = (float*)(ws + LG_OFF);
    int* cnt = (int*)(ws + CNT_OFF);
    _Float16* WxT_f = (_Float16*)(ws + WXT_OFF);
    _Float16* WxT_b = (_Float16*)(ws + WXT_OFF + 4194304ULL);
    _Float16* WhT_f = (_Float16*)(ws + WHT_OFF);
    _Float16* WhT_b = (_Float16*)(ws + WHT_OFF + 2097152ULL);

    init_kernel<<<257, 256, 0, stream>>>(hpack, logits, cnt, b_fc);

    // pre-transpose weights to f16 [n][k]
    transpose_f16<<<dim3(64, 32), 256, 0, stream>>>(Wx_f, WxT_f, 1024, 2048);
    transpose_f16<<<dim3(64, 32), 256, 0, stream>>>(Wx_b, WxT_b, 1024, 2048);
    transpose_f16<<<dim3(64, 16), 256, 0, stream>>>(Wh_f, WhT_f, 512, 2048);
    transpose_f16<<<dim3(64, 16), 256, 0, stream>>>(Wh_b, WhT_b, 512, 2048);

    // phase 1: input projections (MFMA f16)
    gemm_xg<<<dim3(16, 256, 2), 256, 0, stream>>>(
        x, WxT_f, b_f, WxT_b, b_b, xg_f, xg_b);

    // phase 2: persistent recurrence (64 blocks, co-resident)
    lstm_persist<<<64, 512, 0, stream>>>(
        xg_f, xg_b, WhT_f, WhT_b, W_fc, hpack, logits, cnt);

    final_kernel<<<(BB * TT) / 256, 256, 0, stream>>>(logits, out);
}

// Round 4
// 7063.522 us; speedup vs baseline: 5.4998x; 1.2990x over previous
//
#include <hip/hip_runtime.h>
#include <hip/hip_bf16.h>
#include <cstdint>
#include <cstddef>

// Problem constants
#define TT 1024
#define BB 32
#define DD 1024
#define HH 512
#define GG 2048  // 4H

typedef _Float16 f16x8 __attribute__((ext_vector_type(8)));
typedef _Float16 f16x4 __attribute__((ext_vector_type(4)));
typedef float    f32x4 __attribute__((ext_vector_type(4)));

__device__ __forceinline__ float sigm(float x) { return 1.0f / (1.0f + __expf(-x)); }
__device__ __forceinline__ float tanh_fast(float x) { return 2.0f / (1.0f + __expf(-2.0f * x)) - 1.0f; }

// ---------------------------------------------------------------------------
// init: zero packed-h ping-pong buffers (32768 u32) + counters (64 ints),
// seed logits[t*32+b] = b_fc[0] (32768 floats).
// ---------------------------------------------------------------------------
__global__ __launch_bounds__(256) void init_kernel(unsigned int* __restrict__ hp_u,
                                                   float* __restrict__ logits,
                                                   int* __restrict__ cnt,
                                                   const float* __restrict__ b_fc) {
    int i = blockIdx.x * 256 + threadIdx.x;
    if (i < 32768) {
        hp_u[i] = 0u;
    } else if (i < 65536) {
        logits[i - 32768] = b_fc[0];
    } else if (i < 65600) {
        cnt[i - 65536] = 0;
    }
}

// ---------------------------------------------------------------------------
// transpose_f16: in fp32 [K][N] row-major -> out f16 [N][K].
// 32x32 LDS tiles, 256 threads. Used for Wx (1024x2048) and Wh (512x2048).
// ---------------------------------------------------------------------------
__global__ __launch_bounds__(256) void transpose_f16(const float* __restrict__ in,
                                                     _Float16* __restrict__ out,
                                                     int K, int N) {
    __shared__ float tile[32][33];
    const int tx = threadIdx.x & 31, ty = threadIdx.x >> 5;
    const int n0 = blockIdx.x * 32, k0 = blockIdx.y * 32;
#pragma unroll
    for (int j = 0; j < 4; j++)
        tile[ty + 8 * j][tx] = in[(size_t)(k0 + ty + 8 * j) * N + n0 + tx];
    __syncthreads();
#pragma unroll
    for (int j = 0; j < 4; j++)
        out[(size_t)(n0 + ty + 8 * j) * K + k0 + tx] = (_Float16)tile[tx][ty + 8 * j];
}

// ---------------------------------------------------------------------------
// Phase 1: xg = x@Wx + b via MFMA f16 (fp32 accumulate), stored f16.
// Tiles: block = 128(m) x 128(n), 256 threads (4 waves), K-step 64.
// Output layout (recurrence-native):
//   xg[t][blk32][b32][gate4][jl16],  n = gate*512 + blk*16 + jl
// ---------------------------------------------------------------------------
__global__ __launch_bounds__(256) void gemm_xg(const float* __restrict__ x,
                                               const _Float16* __restrict__ WxT_f,
                                               const float* __restrict__ b_f,
                                               const _Float16* __restrict__ WxT_b,
                                               const float* __restrict__ b_b,
                                               _Float16* __restrict__ xg_f,
                                               _Float16* __restrict__ xg_b) {
    const int dir = blockIdx.z;
    const _Float16* __restrict__ WxT = dir ? WxT_b : WxT_f;
    const float* __restrict__ bias = dir ? b_b : b_f;
    _Float16* __restrict__ out = dir ? xg_b : xg_f;

    const int n0 = blockIdx.x * 128;
    const int m0 = blockIdx.y * 128;

    __shared__ _Float16 A_lds[128 * 72];  // [m][k], k padded 64->72
    __shared__ _Float16 B_lds[128 * 72];  // [n][k]

    const int tid = threadIdx.x;
    const int wave = tid >> 6;
    const int lane = tid & 63;
    const int jn = lane & 15;
    const int quad = lane >> 4;

    f32x4 acc[2][8] = {};

    for (int k0 = 0; k0 < DD; k0 += 64) {
        // ---- stage A: 128m x 64k fp32 -> f16 LDS ----
        {
            const int kq = tid & 15;          // float4 within 64 k
            const int mq = tid >> 4;          // 0..15
#pragma unroll
            for (int i = 0; i < 8; i++) {
                const int m = mq + 16 * i;
                const int gm = m0 + m;
                const int t = gm >> 5;
                const int b = gm & 31;
                const float4 v = *(const float4*)(x + ((size_t)b * TT + t) * DD + k0 + kq * 4);
                f16x4 f;
                f.x = (_Float16)v.x; f.y = (_Float16)v.y;
                f.z = (_Float16)v.z; f.w = (_Float16)v.w;
                *(f16x4*)(A_lds + m * 72 + kq * 4) = f;
            }
        }
        // ---- stage B: 128n x 64k f16 (already transposed) ----
        {
            const int kq = tid & 7;           // f16x8 within 64 k
            const int nq = tid >> 3;          // 0..31
#pragma unroll
            for (int i = 0; i < 4; i++) {
                const int n = nq + 32 * i;
                f16x8 w = *(const f16x8*)(WxT + (size_t)(n0 + n) * DD + k0 + kq * 8);
                *(f16x8*)(B_lds + n * 72 + kq * 8) = w;
            }
        }
        __syncthreads();
        // ---- compute ----
#pragma unroll
        for (int kc = 0; kc < 64; kc += 32) {
            const f16x8 a0 = *(const f16x8*)(A_lds + (wave * 32 + jn) * 72 + kc + quad * 8);
            const f16x8 a1 = *(const f16x8*)(A_lds + (wave * 32 + 16 + jn) * 72 + kc + quad * 8);
#pragma unroll
            for (int nt = 0; nt < 8; nt++) {
                const f16x8 bb = *(const f16x8*)(B_lds + (nt * 16 + jn) * 72 + kc + quad * 8);
                acc[0][nt] = __builtin_amdgcn_mfma_f32_16x16x32_f16(a0, bb, acc[0][nt], 0, 0, 0);
                acc[1][nt] = __builtin_amdgcn_mfma_f32_16x16x32_f16(a1, bb, acc[1][nt], 0, 0, 0);
            }
        }
        __syncthreads();
    }

    // ---- epilogue: add bias, store f16 in recurrence layout ----
    float bv[8];
#pragma unroll
    for (int nt = 0; nt < 8; nt++) bv[nt] = bias[n0 + nt * 16 + jn];
#pragma unroll
    for (int mt = 0; mt < 2; mt++) {
#pragma unroll
        for (int r = 0; r < 4; r++) {
            const int m = m0 + wave * 32 + mt * 16 + quad * 4 + r;
            const int t = m >> 5;
            const int b = m & 31;
            const size_t rowbase = ((size_t)t * 32) * 32;  // + blk later
#pragma unroll
            for (int nt = 0; nt < 8; nt++) {
                const int n = n0 + nt * 16 + jn;
                const int g = n >> 9;
                const int blkr = (n & 511) >> 4;
                const int jl = n & 15;
                const float val = acc[mt][nt][r] + bv[nt];
                out[((rowbase + (size_t)blkr * 32 + b)) * 64 + g * 16 + jl] = (_Float16)val;
            }
        }
    }
}

// ---------------------------------------------------------------------------
// Phase 2: persistent bidirectional LSTM recurrence via MFMA.
// 64 blocks x 512 threads; blocks 0..31 = fwd, 32..63 = bwd.
// Wh B-fragments live in VGPRs for all 1024 steps. h exchanged via
// agent-scope (sc0/sc1) atomics, which are read/write-through at the
// coherence point -> NO release/acquire cache-maintenance (buffer_wbl2 /
// buffer_inv) needed: __syncthreads() drains vmcnt(0) per wave, so a
// RELAXED counter add after it is HW-ordered after the h stores.
// ---------------------------------------------------------------------------
__global__ __launch_bounds__(512) void lstm_persist(
    const _Float16* __restrict__ xg_f,
    const _Float16* __restrict__ xg_b,
    const _Float16* __restrict__ WhT_f,
    const _Float16* __restrict__ WhT_b,
    const float* __restrict__ wfc,
    unsigned int* __restrict__ hpack,
    float* __restrict__ logits,
    int* __restrict__ cnt) {

    __shared__ _Float16 h_lds[32 * 520];  // [b][k], k padded -> 33,280 B
    __shared__ float red[4 * 32 * 17];    // [g][b][jl pad 17] -> 8,704 B
    __shared__ int dead;

    const int tid = threadIdx.x;
    const int bid = blockIdx.x;
    const int dir = bid >> 5;
    const int blk = bid & 31;

    const _Float16* __restrict__ xg = dir ? xg_b : xg_f;
    const _Float16* __restrict__ WhT = dir ? WhT_b : WhT_f;
    unsigned int* hp = hpack + dir * 16384;  // [parity][8192] u32
    int* mycnt = cnt + dir * 32;

    // wave roles
    const int lane = tid & 63;
    const int wave = tid >> 6;
    const int mt = wave & 1;       // b-half: rows mt*16..+16
    const int g = wave >> 1;       // gate 0..3
    const int jl16 = lane & 15;
    const int quad = lane >> 4;

    // ---- preload Wh B-fragments into registers (once) ----
    f16x8 bfrag[16];
    {
        const _Float16* wcol = WhT + (size_t)(g * 512 + blk * 16 + jl16) * HH;
#pragma unroll
        for (int i = 0; i < 16; i++)
            bfrag[i] = *(const f16x8*)(wcol + i * 32 + quad * 8);
    }

    // gate-thread role: one (b, jl) per thread
    const int gb = tid >> 4;       // 0..31
    const int gjl = tid & 15;      // 0..15
    float c_reg = 0.0f;
    const float wfc_reg = wfc[dir * 512 + blk * 16 + gjl];

    // xg prefetch for step 0
    float xnext[4];
    {
        const int t0 = dir ? (TT - 1) : 0;
        const size_t base = (((size_t)t0 * 32 + blk) * 32 + gb) * 64 + gjl;
#pragma unroll
        for (int g4 = 0; g4 < 4; g4++) xnext[g4] = (float)xg[base + g4 * 16];
    }

    if (tid == 0) dead = 0;
    unsigned int* hl_u = (unsigned int*)h_lds;
    __syncthreads();

    for (int s = 0; s < TT; s++) {
        const int t = dir ? (TT - 1 - s) : s;

        // ---- stage h(s): 4096 u64 agent-scope loads -> LDS ----
        {
            const unsigned long long* src =
                (const unsigned long long*)(hp + (s & 1) * 8192);
#pragma unroll
            for (int q = 0; q < 8; q++) {
                const int idx = q * 512 + tid;  // 0..4095
                unsigned long long v = __hip_atomic_load(src + idx, __ATOMIC_RELAXED,
                                                         __HIP_MEMORY_SCOPE_AGENT);
                *(unsigned long long*)(hl_u + (idx >> 7) * 260 + (idx & 127) * 2) = v;
            }
        }
        __syncthreads();

        // ---- MFMA: preact tile [16 b x 16 jl] for gate g, b-half mt ----
        // two independent 8-chains to halve dependent-MFMA latency
        {
            f32x4 acc0 = {0.f, 0.f, 0.f, 0.f};
            f32x4 acc1 = {0.f, 0.f, 0.f, 0.f};
            const _Float16* hrow = h_lds + (mt * 16 + jl16) * 520 + quad * 8;
#pragma unroll
            for (int i = 0; i < 8; i++) {
                const f16x8 a0 = *(const f16x8*)(hrow + 32 * i);
                const f16x8 a1 = *(const f16x8*)(hrow + 32 * (i + 8));
                acc0 = __builtin_amdgcn_mfma_f32_16x16x32_f16(a0, bfrag[i], acc0, 0, 0, 0);
                acc1 = __builtin_amdgcn_mfma_f32_16x16x32_f16(a1, bfrag[i + 8], acc1, 0, 0, 0);
            }
            const f32x4 acc = acc0 + acc1;
#pragma unroll
            for (int r = 0; r < 4; r++)
                red[(g * 32 + mt * 16 + quad * 4 + r) * 17 + jl16] = acc[r];
        }
        __syncthreads();

        // ---- gate math + h/c update + fused FC (all 512 threads) ----
        {
            const float p0 = red[(0 * 32 + gb) * 17 + gjl] + xnext[0];
            const float p1 = red[(1 * 32 + gb) * 17 + gjl] + xnext[1];
            const float p2 = red[(2 * 32 + gb) * 17 + gjl] + xnext[2];
            const float p3 = red[(3 * 32 + gb) * 17 + gjl] + xnext[3];

            const float gi = sigm(p0);
            const float gf = sigm(p1);
            const float gc = tanh_fast(p2);
            const float go = sigm(p3);
            c_reg = gf * c_reg + gi * gc;
            const float hval = go * tanh_fast(c_reg);

            // pack f16 pair with jl-neighbor, agent-scope store (sc0/sc1)
            const float hpart = __shfl_xor(hval, 1);
            if ((gjl & 1) == 0) {
                union { struct { _Float16 lo, hi; } h; unsigned int u; } cvt;
                cvt.h.lo = (_Float16)hval;
                cvt.h.hi = (_Float16)hpart;
                unsigned int* dst = hp + ((s + 1) & 1) * 8192;
                __hip_atomic_store(dst + gb * 256 + blk * 8 + (gjl >> 1), cvt.u,
                                   __ATOMIC_RELAXED, __HIP_MEMORY_SCOPE_AGENT);
            }
            // fused final-FC contribution: reduce over this block's 16 jl
            float contrib = hval * wfc_reg;
            contrib += __shfl_xor(contrib, 1);
            contrib += __shfl_xor(contrib, 2);
            contrib += __shfl_xor(contrib, 4);
            contrib += __shfl_xor(contrib, 8);
            if (gjl == 0) atomicAdd(&logits[t * BB + gb], contrib);

            // prefetch xg for next step (overlaps barrier + h exchange)
            if (s + 1 < TT) {
                const int tn = dir ? (TT - 2 - s) : (s + 1);
                const size_t base = (((size_t)tn * 32 + blk) * 32 + gb) * 64 + gjl;
#pragma unroll
                for (int g4 = 0; g4 < 4; g4++) xnext[g4] = (float)xg[base + g4 * 16];
            }
        }

        // ---- per-dir grid barrier: relaxed counter, no cache maintenance ----
        // __syncthreads drains vmcnt(0) per wave -> h stores are at the
        // coherence point before any wave passes; relaxed add is then ordered.
        __syncthreads();
        if (tid == 0) {
            __asm__ volatile("" ::: "memory");  // no compiler reordering
            const int tgt = 32 * (s + 1);
            __hip_atomic_fetch_add(mycnt, 1, __ATOMIC_RELAXED,
                                   __HIP_MEMORY_SCOPE_AGENT);
            int it = 0;
            while (__hip_atomic_load(mycnt, __ATOMIC_RELAXED,
                                     __HIP_MEMORY_SCOPE_AGENT) < tgt) {
                __builtin_amdgcn_s_sleep(1);
                if (++it > (1 << 22)) { dead = 1; break; }  // watchdog valve
            }
            __asm__ volatile("" ::: "memory");
        }
        __syncthreads();
        if (dead) break;  // fail visibly instead of hanging
    }
}

// ---------------------------------------------------------------------------
// Final: out[b][t] = sigmoid(logits[t][b])
// ---------------------------------------------------------------------------
__global__ __launch_bounds__(256) void final_kernel(const float* __restrict__ logits,
                                                    float* __restrict__ out) {
    const int i = blockIdx.x * 256 + threadIdx.x;  // i = b*1024 + t
    const int b = i >> 10;
    const int t = i & 1023;
    out[i] = sigm(logits[t * BB + b]);
}

extern "C" void kernel_launch(void* const* d_in, const int* in_sizes, int n_in,
                              void* d_out, int out_size, void* d_ws, size_t ws_size,
                              hipStream_t stream) {
    const float* x    = (const float*)d_in[0];
    const float* Wx_f = (const float*)d_in[1];
    const float* Wh_f = (const float*)d_in[2];
    const float* b_f  = (const float*)d_in[3];
    const float* Wx_b = (const float*)d_in[4];
    const float* Wh_b = (const float*)d_in[5];
    const float* b_b  = (const float*)d_in[6];
    const float* W_fc = (const float*)d_in[7];
    const float* b_fc = (const float*)d_in[8];
    float* out = (float*)d_out;

    // Workspace layout (bytes):
    //   xg_f  f16 [t][blk][b][gate][jl] : 134,217,728
    //   xg_b  f16 same                  : 134,217,728
    //   hpack u32 [dir][parity][8192]   : 131,072
    //   logits fp32 [T*B]               : 131,072
    //   cnt   int [64]                  : 256 (+pad to 512)
    //   WxT_f f16 [2048][1024]          : 4,194,304
    //   WxT_b f16 [2048][1024]          : 4,194,304
    //   WhT_f f16 [2048][512]           : 2,097,152
    //   WhT_b f16 [2048][512]           : 2,097,152
    const size_t XG = 134217728ULL;
    const size_t HP_OFF   = 2 * XG;                    // 268,435,456
    const size_t LG_OFF   = HP_OFF + 131072ULL;
    const size_t CNT_OFF  = LG_OFF + 131072ULL;
    const size_t WXT_OFF  = CNT_OFF + 512ULL;
    const size_t WHT_OFF  = WXT_OFF + 2 * 4194304ULL;
    const size_t need     = WHT_OFF + 2 * 2097152ULL;
    if (ws_size < need) return;  // fail loudly via mismatch

    uint8_t* ws = (uint8_t*)d_ws;
    _Float16* xg_f = (_Float16*)ws;
    _Float16* xg_b = (_Float16*)(ws + XG);
    unsigned int* hpack = (unsigned int*)(ws + HP_OFF);
    float* logits = (float*)(ws + LG_OFF);
    int* cnt = (int*)(ws + CNT_OFF);
    _Float16* WxT_f = (_Float16*)(ws + WXT_OFF);
    _Float16* WxT_b = (_Float16*)(ws + WXT_OFF + 4194304ULL);
    _Float16* WhT_f = (_Float16*)(ws + WHT_OFF);
    _Float16* WhT_b = (_Float16*)(ws + WHT_OFF + 2097152ULL);

    init_kernel<<<257, 256, 0, stream>>>(hpack, logits, cnt, b_fc);

    // pre-transpose weights to f16 [n][k]
    transpose_f16<<<dim3(64, 32), 256, 0, stream>>>(Wx_f, WxT_f, 1024, 2048);
    transpose_f16<<<dim3(64, 32), 256, 0, stream>>>(Wx_b, WxT_b, 1024, 2048);
    transpose_f16<<<dim3(64, 16), 256, 0, stream>>>(Wh_f, WhT_f, 512, 2048);
    transpose_f16<<<dim3(64, 16), 256, 0, stream>>>(Wh_b, WhT_b, 512, 2048);

    // phase 1: input projections (MFMA f16)
    gemm_xg<<<dim3(16, 256, 2), 256, 0, stream>>>(
        x, WxT_f, b_f, WxT_b, b_b, xg_f, xg_b);

    // phase 2: persistent recurrence (64 blocks, co-resident)
    lstm_persist<<<64, 512, 0, stream>>>(
        xg_f, xg_b, WhT_f, WhT_b, W_fc, hpack, logits, cnt);

    final_kernel<<<(BB * TT) / 256, 256, 0, stream>>>(logits, out);
}

// Round 5
// 5688.530 us; speedup vs baseline: 6.8292x; 1.2417x over previous
//
#include <hip/hip_runtime.h>
#include <hip/hip_bf16.h>
#include <cstdint>
#include <cstddef>

// Problem constants
#define TT 1024
#define BB 32
#define DD 1024
#define HH 512
#define GG 2048  // 4H

typedef _Float16 f16x8 __attribute__((ext_vector_type(8)));
typedef _Float16 f16x4 __attribute__((ext_vector_type(4)));
typedef float    f32x4 __attribute__((ext_vector_type(4)));

__device__ __forceinline__ float sigm(float x) { return 1.0f / (1.0f + __expf(-x)); }
__device__ __forceinline__ float tanh_fast(float x) { return 2.0f / (1.0f + __expf(-2.0f * x)) - 1.0f; }

// ---------------------------------------------------------------------------
// init: zero h ping-pong parity-0 slots (2 dirs x 8192 u32) + flags (64 u32).
// ---------------------------------------------------------------------------
__global__ __launch_bounds__(256) void init_kernel(unsigned int* __restrict__ hp_u,
                                                   unsigned int* __restrict__ flags) {
    int i = blockIdx.x * 256 + threadIdx.x;
    if (i < 8192) {
        hp_u[i] = 0u;                  // dir 0, parity 0
    } else if (i < 16384) {
        hp_u[8192 + i] = 0u;           // dir 1, parity 0 (dir stride 16384)
    } else if (i < 16448) {
        flags[i - 16384] = 0u;
    }
}

// ---------------------------------------------------------------------------
// transpose_f16: in fp32 [K][N] row-major -> out f16 [N][K].
// ---------------------------------------------------------------------------
__global__ __launch_bounds__(256) void transpose_f16(const float* __restrict__ in,
                                                     _Float16* __restrict__ out,
                                                     int K, int N) {
    __shared__ float tile[32][33];
    const int tx = threadIdx.x & 31, ty = threadIdx.x >> 5;
    const int n0 = blockIdx.x * 32, k0 = blockIdx.y * 32;
#pragma unroll
    for (int j = 0; j < 4; j++)
        tile[ty + 8 * j][tx] = in[(size_t)(k0 + ty + 8 * j) * N + n0 + tx];
    __syncthreads();
#pragma unroll
    for (int j = 0; j < 4; j++)
        out[(size_t)(n0 + ty + 8 * j) * K + k0 + tx] = (_Float16)tile[tx][ty + 8 * j];
}

// ---------------------------------------------------------------------------
// Phase 1: xg = x@Wx + b via MFMA f16 (fp32 accumulate), stored f16.
// Output layout (recurrence/chunk-native), indexed by recurrence STEP sidx
// (sidx = t for fwd, 1023-t for bwd):
//   xgv[blk32][b32][jl16][sc128][si8][g4]
//   idx = ((((blk*32+b)*16+jl)*128 + sc)*8 + si)*4 + g
// ---------------------------------------------------------------------------
__global__ __launch_bounds__(256) void gemm_xg(const float* __restrict__ x,
                                               const _Float16* __restrict__ WxT_f,
                                               const float* __restrict__ b_f,
                                               const _Float16* __restrict__ WxT_b,
                                               const float* __restrict__ b_b,
                                               _Float16* __restrict__ xg_f,
                                               _Float16* __restrict__ xg_b) {
    const int dir = blockIdx.z;
    const _Float16* __restrict__ WxT = dir ? WxT_b : WxT_f;
    const float* __restrict__ bias = dir ? b_b : b_f;
    _Float16* __restrict__ out = dir ? xg_b : xg_f;

    const int n0 = blockIdx.x * 128;
    const int m0 = blockIdx.y * 128;

    __shared__ _Float16 A_lds[128 * 72];  // [m][k], k padded 64->72
    __shared__ _Float16 B_lds[128 * 72];  // [n][k]

    const int tid = threadIdx.x;
    const int wave = tid >> 6;
    const int lane = tid & 63;
    const int jn = lane & 15;
    const int quad = lane >> 4;

    f32x4 acc[2][8] = {};

    for (int k0 = 0; k0 < DD; k0 += 64) {
        // ---- stage A: 128m x 64k fp32 -> f16 LDS ----
        {
            const int kq = tid & 15;
            const int mq = tid >> 4;
#pragma unroll
            for (int i = 0; i < 8; i++) {
                const int m = mq + 16 * i;
                const int gm = m0 + m;
                const int t = gm >> 5;
                const int b = gm & 31;
                const float4 v = *(const float4*)(x + ((size_t)b * TT + t) * DD + k0 + kq * 4);
                f16x4 f;
                f.x = (_Float16)v.x; f.y = (_Float16)v.y;
                f.z = (_Float16)v.z; f.w = (_Float16)v.w;
                *(f16x4*)(A_lds + m * 72 + kq * 4) = f;
            }
        }
        // ---- stage B: 128n x 64k f16 (already transposed) ----
        {
            const int kq = tid & 7;
            const int nq = tid >> 3;
#pragma unroll
            for (int i = 0; i < 4; i++) {
                const int n = nq + 32 * i;
                f16x8 w = *(const f16x8*)(WxT + (size_t)(n0 + n) * DD + k0 + kq * 8);
                *(f16x8*)(B_lds + n * 72 + kq * 8) = w;
            }
        }
        __syncthreads();
#pragma unroll
        for (int kc = 0; kc < 64; kc += 32) {
            const f16x8 a0 = *(const f16x8*)(A_lds + (wave * 32 + jn) * 72 + kc + quad * 8);
            const f16x8 a1 = *(const f16x8*)(A_lds + (wave * 32 + 16 + jn) * 72 + kc + quad * 8);
#pragma unroll
            for (int nt = 0; nt < 8; nt++) {
                const f16x8 bb = *(const f16x8*)(B_lds + (nt * 16 + jn) * 72 + kc + quad * 8);
                acc[0][nt] = __builtin_amdgcn_mfma_f32_16x16x32_f16(a0, bb, acc[0][nt], 0, 0, 0);
                acc[1][nt] = __builtin_amdgcn_mfma_f32_16x16x32_f16(a1, bb, acc[1][nt], 0, 0, 0);
            }
        }
        __syncthreads();
    }

    // ---- epilogue: add bias, store f16 in chunk-native layout ----
    const int g = n0 >> 9;                 // gate (same for all 128 n here)
    const int blkbase = (n0 & 511) >> 4;   // recurrence block base
    float bv[8];
#pragma unroll
    for (int nt = 0; nt < 8; nt++) bv[nt] = bias[n0 + nt * 16 + jn];
#pragma unroll
    for (int mt = 0; mt < 2; mt++) {
#pragma unroll
        for (int r = 0; r < 4; r++) {
            const int m = m0 + wave * 32 + mt * 16 + quad * 4 + r;
            const int t = m >> 5;
            const int b = m & 31;
            const int sidx = dir ? (1023 - t) : t;
            const int sc = sidx >> 3, si = sidx & 7;
#pragma unroll
            for (int nt = 0; nt < 8; nt++) {
                const int blk = blkbase + nt;
                const float val = acc[mt][nt][r] + bv[nt];
                const size_t idx =
                    ((((size_t)(blk * 32 + b) * 16 + jn) * 128 + sc) * 8 + si) * 4 + g;
                out[idx] = (_Float16)val;
            }
        }
    }
}

// ---------------------------------------------------------------------------
// Phase 2: persistent bidirectional LSTM recurrence via MFMA.
// 64 blocks x 512 threads; blocks 0..31 = fwd, 32..63 = bwd.
// Wh B-fragments in VGPRs for all steps. xg loaded in 8-step register
// chunks (one 64-B load / thread / 8 steps). h exchanged via agent-scope
// atomics; flag-vector barrier (one relaxed store to arrive, one 32-lane
// load + ballot to detect). FC partials stored f16, reduced later.
// ---------------------------------------------------------------------------
__global__ __launch_bounds__(512, 2) void lstm_persist(
    const _Float16* __restrict__ xg_f,
    const _Float16* __restrict__ xg_b,
    const _Float16* __restrict__ WhT_f,
    const _Float16* __restrict__ WhT_b,
    const float* __restrict__ wfc,
    unsigned int* __restrict__ hpack,
    _Float16* __restrict__ part,
    unsigned int* __restrict__ flags) {

    __shared__ _Float16 h_lds[32 * 520];  // [b][k], padded
    __shared__ float red[4 * 32 * 17];    // [g][b][jl pad 17]
    __shared__ int dead;

    const int tid = threadIdx.x;
    const int bid = blockIdx.x;
    const int dir = bid >> 5;
    const int blk = bid & 31;

    const _Float16* __restrict__ xg = dir ? xg_b : xg_f;
    const _Float16* __restrict__ WhT = dir ? WhT_b : WhT_f;
    unsigned int* hp = hpack + dir * 16384;     // [parity][8192] u32
    unsigned int* myflags = flags + dir * 32;

    // wave roles
    const int lane = tid & 63;
    const int wave = tid >> 6;
    const int mt = wave & 1;       // b-half
    const int g = wave >> 1;       // gate 0..3
    const int jl16 = lane & 15;
    const int quad = lane >> 4;

    // ---- preload Wh B-fragments into registers (once) ----
    f16x8 bfrag[16];
    {
        const _Float16* wcol = WhT + (size_t)(g * 512 + blk * 16 + jl16) * HH;
#pragma unroll
        for (int i = 0; i < 16; i++)
            bfrag[i] = *(const f16x8*)(wcol + i * 32 + quad * 8);
    }

    // gate-thread role: one (b, jl) per thread
    const int gb = tid >> 4;       // 0..31
    const int gjl = tid & 15;      // 0..15
    float c_reg = 0.0f;
    const float wfc_reg = wfc[dir * 512 + blk * 16 + gjl];

    if (tid == 0) dead = 0;
    unsigned int* hl_u = (unsigned int*)h_lds;
    const _Float16* xbase = xg + (((size_t)(blk * 32 + gb) * 16 + gjl) * 128) * 32;

    __syncthreads();

    for (int sc = 0; sc < 128; sc++) {
        // ---- xg chunk: 64 B -> 4 f16x8 regs, covers next 8 steps ----
        f16x8 xchunk[4];
        {
            const f16x8* src = (const f16x8*)(xbase + sc * 32);
#pragma unroll
            for (int q = 0; q < 4; q++) xchunk[q] = src[q];
        }

#pragma unroll
        for (int si = 0; si < 8; si++) {
            const int s = sc * 8 + si;
            const int t = dir ? (1023 - s) : s;

            // ---- wait for all producers of h(s) (skip s=0: pre-zeroed) ----
            if (s > 0) {
                if (wave == 0) {
                    const unsigned int tgt = (unsigned int)s;
                    int it = 0;
                    for (;;) {
                        unsigned int v = tgt;
                        if (lane < 32)
                            v = __hip_atomic_load(myflags + lane, __ATOMIC_RELAXED,
                                                  __HIP_MEMORY_SCOPE_AGENT);
                        unsigned long long mask = __ballot(v >= tgt);
                        if (mask == ~0ull) break;
                        __builtin_amdgcn_s_sleep(1);
                        if (++it > (1 << 22)) { if (tid == 0) dead = 1; break; }
                    }
                }
                __syncthreads();
                if (dead) goto finish;  // uniform; fail visibly, not a hang
            }

            // ---- stage h(s): 4096 u64 agent-scope loads -> LDS ----
            {
                const unsigned long long* src =
                    (const unsigned long long*)(hp + (s & 1) * 8192);
#pragma unroll
                for (int q = 0; q < 8; q++) {
                    const int idx = q * 512 + tid;  // 0..4095
                    unsigned long long v = __hip_atomic_load(src + idx, __ATOMIC_RELAXED,
                                                             __HIP_MEMORY_SCOPE_AGENT);
                    *(unsigned long long*)(hl_u + (idx >> 7) * 260 + (idx & 127) * 2) = v;
                }
            }
            __syncthreads();

            // ---- MFMA: preact tile [16b x 16jl], two independent 8-chains ----
            {
                f32x4 acc0 = {0.f, 0.f, 0.f, 0.f};
                f32x4 acc1 = {0.f, 0.f, 0.f, 0.f};
                const _Float16* hrow = h_lds + (mt * 16 + jl16) * 520 + quad * 8;
#pragma unroll
                for (int i = 0; i < 8; i++) {
                    const f16x8 a0 = *(const f16x8*)(hrow + 32 * i);
                    const f16x8 a1 = *(const f16x8*)(hrow + 32 * (i + 8));
                    acc0 = __builtin_amdgcn_mfma_f32_16x16x32_f16(a0, bfrag[i], acc0, 0, 0, 0);
                    acc1 = __builtin_amdgcn_mfma_f32_16x16x32_f16(a1, bfrag[i + 8], acc1, 0, 0, 0);
                }
                const f32x4 acc = acc0 + acc1;
#pragma unroll
                for (int r = 0; r < 4; r++)
                    red[(g * 32 + mt * 16 + quad * 4 + r) * 17 + jl16] = acc[r];
            }
            __syncthreads();

            // ---- gate math + h/c update + FC partial (all 512 threads) ----
            {
                const float p0 = red[(0 * 32 + gb) * 17 + gjl] + (float)xchunk[si >> 1][(si & 1) * 4 + 0];
                const float p1 = red[(1 * 32 + gb) * 17 + gjl] + (float)xchunk[si >> 1][(si & 1) * 4 + 1];
                const float p2 = red[(2 * 32 + gb) * 17 + gjl] + (float)xchunk[si >> 1][(si & 1) * 4 + 2];
                const float p3 = red[(3 * 32 + gb) * 17 + gjl] + (float)xchunk[si >> 1][(si & 1) * 4 + 3];

                const float gi = sigm(p0);
                const float gf = sigm(p1);
                const float gc = tanh_fast(p2);
                const float go = sigm(p3);
                c_reg = gf * c_reg + gi * gc;
                const float hval = go * tanh_fast(c_reg);

                // pack f16 pair with jl-neighbor, agent-scope store
                const float hpart = __shfl_xor(hval, 1);
                if ((gjl & 1) == 0) {
                    union { struct { _Float16 lo, hi; } h; unsigned int u; } cvt;
                    cvt.h.lo = (_Float16)hval;
                    cvt.h.hi = (_Float16)hpart;
                    unsigned int* dst = hp + ((s + 1) & 1) * 8192;
                    __hip_atomic_store(dst + gb * 256 + blk * 8 + (gjl >> 1), cvt.u,
                                       __ATOMIC_RELAXED, __HIP_MEMORY_SCOPE_AGENT);
                }
                // FC partial for this block's 16 jl: plain f16 store, no RMW
                float contrib = hval * wfc_reg;
                contrib += __shfl_xor(contrib, 1);
                contrib += __shfl_xor(contrib, 2);
                contrib += __shfl_xor(contrib, 4);
                contrib += __shfl_xor(contrib, 8);
                if (gjl == 0)
                    part[(size_t)(t * 32 + gb) * 64 + dir * 32 + blk] = (_Float16)contrib;
            }

            // ---- arrive: drain (syncthreads waits vmcnt0/wave), set flag ----
            __syncthreads();
            if (tid == 0)
                __hip_atomic_store(myflags + blk, (unsigned int)(s + 1),
                                   __ATOMIC_RELAXED, __HIP_MEMORY_SCOPE_AGENT);
        }
    }
finish:;
}

// ---------------------------------------------------------------------------
// Final: out[b][t] = sigmoid(b_fc + sum over 64 partials part[t][b][*])
// ---------------------------------------------------------------------------
__global__ __launch_bounds__(256) void fc_final(const _Float16* __restrict__ part,
                                                const float* __restrict__ b_fc,
                                                float* __restrict__ out) {
    const int i = blockIdx.x * 256 + threadIdx.x;  // i = b*1024 + t
    const int b = i >> 10;
    const int t = i & 1023;
    const f16x8* p = (const f16x8*)(part + (size_t)(t * 32 + b) * 64);
    float acc = b_fc[0];
#pragma unroll
    for (int q = 0; q < 8; q++) {
        const f16x8 v = p[q];
#pragma unroll
        for (int e = 0; e < 8; e++) acc += (float)v[e];
    }
    out[i] = sigm(acc);
}

extern "C" void kernel_launch(void* const* d_in, const int* in_sizes, int n_in,
                              void* d_out, int out_size, void* d_ws, size_t ws_size,
                              hipStream_t stream) {
    const float* x    = (const float*)d_in[0];
    const float* Wx_f = (const float*)d_in[1];
    const float* Wh_f = (const float*)d_in[2];
    const float* b_f  = (const float*)d_in[3];
    const float* Wx_b = (const float*)d_in[4];
    const float* Wh_b = (const float*)d_in[5];
    const float* b_b  = (const float*)d_in[6];
    const float* W_fc = (const float*)d_in[7];
    const float* b_fc = (const float*)d_in[8];
    float* out = (float*)d_out;

    // Workspace layout (bytes):
    //   xgv_f f16 chunk-native          : 134,217,728
    //   xgv_b f16 chunk-native          : 134,217,728
    //   hpack u32 [dir][parity][8192]   : 131,072
    //   flags u32 [64] (+pad to 512)    : 512
    //   WxT_f f16 [2048][1024]          : 4,194,304   <- `part` (4 MB) ALIASES
    //   WxT_b f16 [2048][1024]          : 4,194,304      this region: WxT is
    //   WhT_f f16 [2048][512]           : 2,097,152      dead after gemm_xg,
    //   WhT_b f16 [2048][512]           : 2,097,152      part written in lstm.
    const size_t XG = 134217728ULL;
    const size_t HP_OFF   = 2 * XG;                 // 268,435,456
    const size_t FLAG_OFF = HP_OFF + 131072ULL;     // 268,566,528
    const size_t WXT_OFF  = FLAG_OFF + 512ULL;      // 268,567,040
    const size_t WHT_OFF  = WXT_OFF + 2 * 4194304ULL;
    const size_t need     = WHT_OFF + 2 * 2097152ULL;  // 281,149,952
    if (ws_size < need) return;  // fail loudly via mismatch

    uint8_t* ws = (uint8_t*)d_ws;
    _Float16* xg_f = (_Float16*)ws;
    _Float16* xg_b = (_Float16*)(ws + XG);
    unsigned int* hpack = (unsigned int*)(ws + HP_OFF);
    unsigned int* flags = (unsigned int*)(ws + FLAG_OFF);
    _Float16* WxT_f = (_Float16*)(ws + WXT_OFF);
    _Float16* WxT_b = (_Float16*)(ws + WXT_OFF + 4194304ULL);
    _Float16* WhT_f = (_Float16*)(ws + WHT_OFF);
    _Float16* WhT_b = (_Float16*)(ws + WHT_OFF + 2097152ULL);
    _Float16* part  = (_Float16*)(ws + WXT_OFF);  // alias, disjoint lifetime

    init_kernel<<<65, 256, 0, stream>>>(hpack, flags);

    // pre-transpose weights to f16 [n][k]
    transpose_f16<<<dim3(64, 32), 256, 0, stream>>>(Wx_f, WxT_f, 1024, 2048);
    transpose_f16<<<dim3(64, 32), 256, 0, stream>>>(Wx_b, WxT_b, 1024, 2048);
    transpose_f16<<<dim3(64, 16), 256, 0, stream>>>(Wh_f, WhT_f, 512, 2048);
    transpose_f16<<<dim3(64, 16), 256, 0, stream>>>(Wh_b, WhT_b, 512, 2048);

    // phase 1: input projections (MFMA f16)
    gemm_xg<<<dim3(16, 256, 2), 256, 0, stream>>>(
        x, WxT_f, b_f, WxT_b, b_b, xg_f, xg_b);

    // phase 2: persistent recurrence (64 blocks, co-resident)
    lstm_persist<<<64, 512, 0, stream>>>(
        xg_f, xg_b, WhT_f, WhT_b, W_fc, hpack, part, flags);

    // epilogue: reduce FC partials + bias + sigmoid
    fc_final<<<(BB * TT) / 256, 256, 0, stream>>>(part, b_fc, out);
}